// Round 3
// baseline (1496.269 us; speedup 1.0000x reference)
//
#include <hip/hip_runtime.h>
#include <stdint.h>
#include <stddef.h>

#define Bsz 16384
#define Hsz 512
#define KG 1536   // K of gemm2 == row stride of A
#define KA 1024   // K of gemm1
#define NT 48     // gemm2 K tiles of 32

typedef float f32x4 __attribute__((ext_vector_type(4)));
typedef short bf16x8 __attribute__((ext_vector_type(8)));
typedef unsigned short u16;
typedef unsigned int u32;

__device__ __forceinline__ u16 f2bf(float f) {
  union { float f; unsigned u; } v; v.f = f;
  return (u16)((v.u + 0x7fffu + ((v.u >> 16) & 1u)) >> 16);
}
__device__ __forceinline__ float bf2f(u16 h) {
  union { unsigned u; float f; } v; v.u = ((unsigned)h) << 16;
  return v.f;
}
__device__ __forceinline__ float sigm(float x) {
  return 1.0f / (1.0f + __expf(-x));
}
__device__ __forceinline__ float tanh_(float x) {
  x = fminf(fmaxf(x, -15.0f), 15.0f);
  float e = __expf(2.0f * x);
  return (e - 1.0f) / (e + 1.0f);
}

__device__ __forceinline__ void gload_lds16(const u16* g, u16* l) {
  __builtin_amdgcn_global_load_lds(
      (__attribute__((address_space(1))) void*)(g),
      (__attribute__((address_space(3))) void*)(l), 16, 0, 0);
}

#define VMCNT(n) asm volatile("s_waitcnt vmcnt(" #n ")" ::: "memory")

// ---- cast h_prev | x_t into bf16 A[B][1536] (cols 0..1023) ----
__global__ __launch_bounds__(256) void prep_A_kernel(
    const float* __restrict__ h_prev, const float* __restrict__ x_t,
    u16* __restrict__ A) {
  const int b = blockIdx.x;
  const int q = threadIdx.x;
  const int qq = q & 127;
  const float4* src = (q < 128) ? (const float4*)h_prev : (const float4*)x_t;
  float4 v = src[(size_t)b * 128 + qq];
  ushort4 o;
  o.x = f2bf(v.x); o.y = f2bf(v.y); o.z = f2bf(v.z); o.w = f2bf(v.w);
  *(ushort4*)(A + (size_t)b * KG + (size_t)q * 4) = o;
}

// ---- transpose-cast: in[R][C] fp32 -> out[C][R] bf16 ----
__global__ __launch_bounds__(256) void transpose_cast_kernel(
    const float* __restrict__ in, u16* __restrict__ out, int R, int C) {
  __shared__ float tile[32][33];
  const int c0 = blockIdx.x * 32;
  const int r0 = blockIdx.y * 32;
  const int tx = threadIdx.x;
  const int ty = threadIdx.y;
  #pragma unroll
  for (int i = ty; i < 32; i += 8)
    tile[i][tx] = in[(size_t)(r0 + i) * C + (c0 + tx)];
  __syncthreads();
  #pragma unroll
  for (int i = ty; i < 32; i += 8)
    out[(size_t)(c0 + i) * R + (r0 + tx)] = f2bf(tile[tx][i]);
}

// ---- GEMM1: s = tanh(A[:,0:1024] @ Wst^T + delta*ws_last + bs) -> A[:,1024:1536]
__global__ __launch_bounds__(256, 2) void gemm1_kernel(
    const u16* __restrict__ A, const u16* __restrict__ Wst,
    const float* __restrict__ Ws, const float* __restrict__ bs,
    const float* __restrict__ delta, u16* __restrict__ Aout) {
  __shared__ __attribute__((aligned(16))) u16 Als[128][32];
  __shared__ __attribute__((aligned(16))) u16 Bls[128][32];
  const int t = threadIdx.x;
  const int w = t >> 6, l = t & 63;
  const int bm0 = blockIdx.y * 128;
  const int bn0 = blockIdx.x * 128;
  const int wm = w >> 1, wn = w & 1;

  f32x4 zv = {0.f, 0.f, 0.f, 0.f};
  f32x4 acc[4][4];
  #pragma unroll
  for (int i = 0; i < 4; ++i)
    #pragma unroll
    for (int j = 0; j < 4; ++j) acc[i][j] = zv;

  const int r = t >> 2, q = t & 3;
  const u16* gA0 = A + (size_t)(bm0 + r) * KG + q * 8;
  const u16* gA1 = A + (size_t)(bm0 + 64 + r) * KG + q * 8;
  const u16* gB0 = Wst + (size_t)(bn0 + r) * KA + q * 8;
  const u16* gB1 = Wst + (size_t)(bn0 + 64 + r) * KA + q * 8;
  u16* lA0 = &Als[0][0] + w * 512;
  u16* lA1 = &Als[0][0] + 2048 + w * 512;
  u16* lB0 = &Bls[0][0] + w * 512;
  u16* lB1 = &Bls[0][0] + 2048 + w * 512;

  const int frow = l & 15;
  const int kofs = (l >> 4) * 8;

  for (int kt = 0; kt < KA / 32; ++kt) {
    const int ko = kt * 32;
    gload_lds16(gA0 + ko, lA0);
    gload_lds16(gA1 + ko, lA1);
    gload_lds16(gB0 + ko, lB0);
    gload_lds16(gB1 + ko, lB1);
    __syncthreads();
    bf16x8 af[4], bfv[4];
    #pragma unroll
    for (int mi = 0; mi < 4; ++mi)
      af[mi] = *(const bf16x8*)&Als[wm * 64 + mi * 16 + frow][kofs];
    #pragma unroll
    for (int ni = 0; ni < 4; ++ni)
      bfv[ni] = *(const bf16x8*)&Bls[wn * 64 + ni * 16 + frow][kofs];
    #pragma unroll
    for (int mi = 0; mi < 4; ++mi)
      #pragma unroll
      for (int ni = 0; ni < 4; ++ni)
        acc[mi][ni] = __builtin_amdgcn_mfma_f32_16x16x32_bf16(
            af[mi], bfv[ni], acc[mi][ni], 0, 0, 0);
    __syncthreads();
  }

  #pragma unroll
  for (int ni = 0; ni < 4; ++ni) {
    const int col = bn0 + wn * 64 + ni * 16 + (l & 15);
    const float wsl = Ws[(size_t)1024 * 512 + col];
    const float bsv = bs[col];
    #pragma unroll
    for (int mi = 0; mi < 4; ++mi) {
      #pragma unroll
      for (int rr = 0; rr < 4; ++rr) {
        const int row = bm0 + wm * 64 + mi * 16 + (l >> 4) * 4 + rr;
        const float z = acc[mi][ni][rr] + delta[row] * wsl + bsv;
        Aout[(size_t)row * KG + 1024 + col] = f2bf(tanh_(z));
      }
    }
  }
}

// ---- GEMM2: BM=256, BH=64 (eff N 320), BK=32, 2 LDS buffers, depth 2 ----
// 2 blocks/CU (72KB LDS). Waves 0-3 stage A (4 loads/tile), 4-7 stage B (5).
// Counted vmcnt: A waves wait vmcnt(4), B waves vmcnt(5) = tile t landed,
// tile t+1 in flight. STAGE(t+2) after barrier2 (buffer t&1 then free).
// LDS chunk swizzle (both-sides): store global chunk c^((row>>1)&3) at
// chunk c (pre-swizzled global src, linear LDS dest); read kq^((frow>>1)&3).
__global__ __launch_bounds__(512, 4) void gemm2_8ph(
    const u16* __restrict__ A, const u16* __restrict__ Wgt,
    const float* __restrict__ bg, const float* __restrict__ c_prev,
    float* __restrict__ out) {
  __shared__ __attribute__((aligned(16))) u16 LDSA[2][256 * 32];
  __shared__ __attribute__((aligned(16))) u16 LDSB[2][320 * 32];

  const int t5 = threadIdx.x;
  const int w = t5 >> 6;
  const int l = t5 & 63;

  const int bid = blockIdx.x;   // 512 blocks
  const int hb = bid & 7;       // same h-panel -> same XCD (round-robin dispatch)
  const int rb = bid >> 3;
  const int bm0 = rb * 256;
  const int h0 = hb * 64;

  const bool isA = (w < 4);

  const u16* gs0 = nullptr; const u16* gs1 = nullptr; const u16* gs2 = nullptr;
  const u16* gs3 = nullptr; const u16* gs4 = nullptr;
  u32 lo0 = 0, lo1 = 0, lo2 = 0, lo3 = 0, lo4 = 0;

  if (isA) {
#define MKA(s, gp, lo) { int idx = w * 256 + (s) * 64 + l; int row = idx >> 2; \
    int ch = (idx & 3) ^ ((idx >> 3) & 3); \
    gp = A + (size_t)(bm0 + row) * KG + ch * 8; lo = (u32)(w * 256 + (s) * 64) * 8; }
    MKA(0, gs0, lo0) MKA(1, gs1, lo1) MKA(2, gs2, lo2) MKA(3, gs3, lo3)
#undef MKA
  } else {
#define MKB(s, gp, lo) { int idx = (w - 4) * 320 + (s) * 64 + l; int rbw = idx >> 2; \
    int ch = (idx & 3) ^ ((idx >> 3) & 3); \
    int g = rbw >> 6; int hl = rbw & 63; \
    gp = Wgt + (size_t)(g * Hsz + h0 + hl) * KG + ch * 8; \
    lo = (u32)((w - 4) * 320 + (s) * 64) * 8; }
    MKB(0, gs0, lo0) MKB(1, gs1, lo1) MKB(2, gs2, lo2) MKB(3, gs3, lo3) MKB(4, gs4, lo4)
#undef MKB
  }

#define STAGE(kt) { const int _b = (kt) & 1; \
    if (isA) { \
      gload_lds16(gs0 + (size_t)(kt) * 32, &LDSA[_b][lo0]); \
      gload_lds16(gs1 + (size_t)(kt) * 32, &LDSA[_b][lo1]); \
      gload_lds16(gs2 + (size_t)(kt) * 32, &LDSA[_b][lo2]); \
      gload_lds16(gs3 + (size_t)(kt) * 32, &LDSA[_b][lo3]); \
    } else { \
      gload_lds16(gs0 + (size_t)(kt) * 32, &LDSB[_b][lo0]); \
      gload_lds16(gs1 + (size_t)(kt) * 32, &LDSB[_b][lo1]); \
      gload_lds16(gs2 + (size_t)(kt) * 32, &LDSB[_b][lo2]); \
      gload_lds16(gs3 + (size_t)(kt) * 32, &LDSB[_b][lo3]); \
      gload_lds16(gs4 + (size_t)(kt) * 32, &LDSB[_b][lo4]); \
    } }

  f32x4 zv = {0.f, 0.f, 0.f, 0.f};
  f32x4 acc[8][5];
  #pragma unroll
  for (int mi = 0; mi < 8; ++mi)
    #pragma unroll
    for (int g = 0; g < 5; ++g) acc[mi][g] = zv;

  // prologue: tiles 0,1 in flight
  STAGE(0) STAGE(1)

  const int wm = w >> 2;
  const int wn = w & 3;
  const int frow = l & 15;
  const int kq = l >> 4;
  const u32 axor = (u32)((kq ^ ((frow >> 1) & 3)) << 3);
  const u32 abase = (u32)(wm * 128 + frow) * 32 + axor;
  const u32 bbase = (u32)(wn * 16 + frow) * 32 + axor;

  for (int t = 0; t < NT; ++t) {
    const int rem = NT - 1 - t;
    // wait for tile t's loads (all waves' own loads for tile t landed)
    if (isA) { if (rem >= 1) VMCNT(4); else VMCNT(0); }
    else     { if (rem >= 1) VMCNT(5); else VMCNT(0); }
    __builtin_amdgcn_s_barrier();
    asm volatile("" ::: "memory");

    const int bt = t & 1;
    const u16* As = &LDSA[bt][0];
    const u16* Bs = &LDSB[bt][0];
    bf16x8 af[8];
    #pragma unroll
    for (int mi = 0; mi < 8; ++mi)
      af[mi] = *(const bf16x8*)&As[abase + mi * 512];
    __builtin_amdgcn_s_setprio(1);
    #pragma unroll
    for (int g = 0; g < 5; ++g) {
      bf16x8 bf = *(const bf16x8*)&Bs[bbase + g * 2048];
      #pragma unroll
      for (int mi = 0; mi < 8; ++mi)
        acc[mi][g] = __builtin_amdgcn_mfma_f32_16x16x32_bf16(
            af[mi], bf, acc[mi][g], 0, 0, 0);
    }
    __builtin_amdgcn_s_setprio(0);
    asm volatile("" ::: "memory");
    __builtin_amdgcn_s_barrier();
    // stage tile t+2 into the buffer just consumed
    if (rem >= 2) STAGE(t + 2)
  }
#undef STAGE

  const int hc = h0 + wn * 16 + frow;
  const float b_f = bg[hc];
  const float b_i = bg[Hsz + hc];
  const float b_T = bg[2 * Hsz + hc];
  const float b_z = bg[3 * Hsz + hc];
  const float b_o = bg[4 * Hsz + hc];
  #pragma unroll
  for (int mi = 0; mi < 8; ++mi) {
    #pragma unroll
    for (int rr = 0; rr < 4; ++rr) {
      const int row = bm0 + wm * 128 + mi * 16 + kq * 4 + rr;
      const float fg = sigm(acc[mi][0][rr] + b_f);
      const float ig = sigm(acc[mi][1][rr] + b_i);
      const float Tg = sigm(acc[mi][2][rr] + b_T);
      const float zg = tanh_(acc[mi][3][rr] + b_z);
      const float og = sigm(acc[mi][4][rr] + b_o);
      const float cp = c_prev[(size_t)row * Hsz + hc];
      const float st = bf2f(A[(size_t)row * KG + 1024 + hc]);
      const float c = fg * cp + ig * zg + Tg * st;
      const float h = og * tanh_(c);
      out[(size_t)row * Hsz + hc] = h;
      out[(size_t)Bsz * Hsz + (size_t)row * Hsz + hc] = c;
    }
  }
}

extern "C" void kernel_launch(void* const* d_in, const int* in_sizes, int n_in,
                              void* d_out, int out_size, void* d_ws, size_t ws_size,
                              hipStream_t stream) {
  const float* x_t    = (const float*)d_in[0];
  const float* delta  = (const float*)d_in[1];
  const float* h_prev = (const float*)d_in[2];
  const float* c_prev = (const float*)d_in[3];
  const float* Ws     = (const float*)d_in[4];
  const float* bs     = (const float*)d_in[5];
  const float* Wg     = (const float*)d_in[6];
  const float* bg     = (const float*)d_in[7];
  float* out = (float*)d_out;

  char* wsb = (char*)d_ws;
  u16* A   = (u16*)(wsb);                          // [16384][1536] bf16
  u16* Wst = (u16*)(wsb + (size_t)50331648);       // [512][1024]  bf16
  u16* Wgt = (u16*)(wsb + (size_t)51380224);       // [2560][1536] bf16

  prep_A_kernel<<<dim3(16384), dim3(256), 0, stream>>>(h_prev, x_t, A);
  transpose_cast_kernel<<<dim3(16, 32), dim3(32, 8), 0, stream>>>(Ws, Wst, 1024, 512);
  transpose_cast_kernel<<<dim3(80, 48), dim3(32, 8), 0, stream>>>(Wg, Wgt, 1536, 2560);
  gemm1_kernel<<<dim3(4, 128), dim3(256), 0, stream>>>(A, Wst, Ws, bs, delta, A);
  gemm2_8ph<<<dim3(512), dim3(512), 0, stream>>>(A, Wgt, bg, c_prev, out);
}

// Round 4
// 211.415 us; speedup vs baseline: 7.0774x; 7.0774x over previous
//
#include <hip/hip_runtime.h>
#include <stdint.h>
#include <stddef.h>

#define Bsz 16384
#define Hsz 512
#define KG 1536   // K of gemm2 == row stride of A
#define KA 1024   // K of gemm1
#define NT2 24    // gemm2 K tiles of 64

typedef float f32x4 __attribute__((ext_vector_type(4)));
typedef short bf16x8 __attribute__((ext_vector_type(8)));
typedef unsigned short u16;
typedef unsigned int u32;

__device__ __forceinline__ u16 f2bf(float f) {
  union { float f; unsigned u; } v; v.f = f;
  return (u16)((v.u + 0x7fffu + ((v.u >> 16) & 1u)) >> 16);
}
__device__ __forceinline__ float bf2f(u16 h) {
  union { unsigned u; float f; } v; v.u = ((unsigned)h) << 16;
  return v.f;
}
__device__ __forceinline__ float sigm(float x) {
  return 1.0f / (1.0f + __expf(-x));
}
__device__ __forceinline__ float tanh_(float x) {
  x = fminf(fmaxf(x, -15.0f), 15.0f);
  float e = __expf(2.0f * x);
  return (e - 1.0f) / (e + 1.0f);
}

__device__ __forceinline__ void gload_lds16(const u16* g, u16* l) {
  __builtin_amdgcn_global_load_lds(
      (__attribute__((address_space(1))) void*)(g),
      (__attribute__((address_space(3))) void*)(l), 16, 0, 0);
}

#define VMCNT(n) asm volatile("s_waitcnt vmcnt(" #n ")" ::: "memory")
#define BAR() { asm volatile("" ::: "memory"); __builtin_amdgcn_s_barrier(); \
                asm volatile("" ::: "memory"); }

// ---- cast h_prev | x_t into bf16 A[B][1536] (cols 0..1023) ----
__global__ __launch_bounds__(256) void prep_A_kernel(
    const float* __restrict__ h_prev, const float* __restrict__ x_t,
    u16* __restrict__ A) {
  const int b = blockIdx.x;
  const int q = threadIdx.x;
  const int qq = q & 127;
  const float4* src = (q < 128) ? (const float4*)h_prev : (const float4*)x_t;
  float4 v = src[(size_t)b * 128 + qq];
  ushort4 o;
  o.x = f2bf(v.x); o.y = f2bf(v.y); o.z = f2bf(v.z); o.w = f2bf(v.w);
  *(ushort4*)(A + (size_t)b * KG + (size_t)q * 4) = o;
}

// ---- transpose-cast: in[R][C] fp32 -> out[C][R] bf16 ----
__global__ __launch_bounds__(256) void transpose_cast_kernel(
    const float* __restrict__ in, u16* __restrict__ out, int R, int C) {
  __shared__ float tile[32][33];
  const int c0 = blockIdx.x * 32;
  const int r0 = blockIdx.y * 32;
  const int tx = threadIdx.x;
  const int ty = threadIdx.y;
  #pragma unroll
  for (int i = ty; i < 32; i += 8)
    tile[i][tx] = in[(size_t)(r0 + i) * C + (c0 + tx)];
  __syncthreads();
  #pragma unroll
  for (int i = ty; i < 32; i += 8)
    out[(size_t)(c0 + i) * R + (r0 + tx)] = f2bf(tile[tx][i]);
}

// ---- GEMM1: s = tanh(A[:,0:1024] @ Wst^T + delta*ws_last + bs) -> A[:,1024:1536]
__global__ __launch_bounds__(256, 2) void gemm1_kernel(
    const u16* __restrict__ A, const u16* __restrict__ Wst,
    const float* __restrict__ Ws, const float* __restrict__ bs,
    const float* __restrict__ delta, u16* __restrict__ Aout) {
  __shared__ __attribute__((aligned(16))) u16 Als[128][32];
  __shared__ __attribute__((aligned(16))) u16 Bls[128][32];
  const int t = threadIdx.x;
  const int w = t >> 6, l = t & 63;
  const int bm0 = blockIdx.y * 128;
  const int bn0 = blockIdx.x * 128;
  const int wm = w >> 1, wn = w & 1;

  f32x4 zv = {0.f, 0.f, 0.f, 0.f};
  f32x4 acc[4][4];
  #pragma unroll
  for (int i = 0; i < 4; ++i)
    #pragma unroll
    for (int j = 0; j < 4; ++j) acc[i][j] = zv;

  const int r = t >> 2, q = t & 3;
  const u16* gA0 = A + (size_t)(bm0 + r) * KG + q * 8;
  const u16* gA1 = A + (size_t)(bm0 + 64 + r) * KG + q * 8;
  const u16* gB0 = Wst + (size_t)(bn0 + r) * KA + q * 8;
  const u16* gB1 = Wst + (size_t)(bn0 + 64 + r) * KA + q * 8;
  u16* lA0 = &Als[0][0] + w * 512;
  u16* lA1 = &Als[0][0] + 2048 + w * 512;
  u16* lB0 = &Bls[0][0] + w * 512;
  u16* lB1 = &Bls[0][0] + 2048 + w * 512;

  const int frow = l & 15;
  const int kofs = (l >> 4) * 8;

  for (int kt = 0; kt < KA / 32; ++kt) {
    const int ko = kt * 32;
    gload_lds16(gA0 + ko, lA0);
    gload_lds16(gA1 + ko, lA1);
    gload_lds16(gB0 + ko, lB0);
    gload_lds16(gB1 + ko, lB1);
    __syncthreads();
    bf16x8 af[4], bfv[4];
    #pragma unroll
    for (int mi = 0; mi < 4; ++mi)
      af[mi] = *(const bf16x8*)&Als[wm * 64 + mi * 16 + frow][kofs];
    #pragma unroll
    for (int ni = 0; ni < 4; ++ni)
      bfv[ni] = *(const bf16x8*)&Bls[wn * 64 + ni * 16 + frow][kofs];
    #pragma unroll
    for (int mi = 0; mi < 4; ++mi)
      #pragma unroll
      for (int ni = 0; ni < 4; ++ni)
        acc[mi][ni] = __builtin_amdgcn_mfma_f32_16x16x32_bf16(
            af[mi], bfv[ni], acc[mi][ni], 0, 0, 0);
    __syncthreads();
  }

  #pragma unroll
  for (int ni = 0; ni < 4; ++ni) {
    const int col = bn0 + wn * 64 + ni * 16 + (l & 15);
    const float wsl = Ws[(size_t)1024 * 512 + col];
    const float bsv = bs[col];
    #pragma unroll
    for (int mi = 0; mi < 4; ++mi) {
      #pragma unroll
      for (int rr = 0; rr < 4; ++rr) {
        const int row = bm0 + wm * 64 + mi * 16 + (l >> 4) * 4 + rr;
        const float z = acc[mi][ni][rr] + delta[row] * wsl + bsv;
        Aout[(size_t)row * KG + 1024 + col] = f2bf(tanh_(z));
      }
    }
  }
}

// ---- GEMM2, 4-phase fine-interleave (m201-style adapted) ----
// BM=256, N=320 (5 gates x 64 h), BK=64, NT2=24, 2 LDS buffers (144KB),
// 1 block/CU, 8 waves (2M x 4N), per-wave C = 128x80, acc[8][5] f32x4.
// Chunk swizzle: LDS[r][c] holds G[r][c ^ (r&7)] (16B chunks, 8/row).
// Stage: pre-swizzled global src, linear LDS dest (gload_lds constraint).
// Read: chunk (kh*4+kq) ^ (frow&7)  ->  addr XOR 32 u16 flips kh.
// Per tile: vmcnt(8)+bar, then 4 phases {ds_reads; setprio1; 20 MFMA;
// setprio0; bar}, then STAGE(t+2) into the just-freed buffer.
__global__ __launch_bounds__(512, 2) void gemm2_8ph(
    const u16* __restrict__ A, const u16* __restrict__ Wgt,
    const float* __restrict__ bg, const float* __restrict__ c_prev,
    float* __restrict__ out) {
  __shared__ __attribute__((aligned(16))) u16 LDSA[2][256 * 64];  // 64 KB
  __shared__ __attribute__((aligned(16))) u16 LDSB[2][320 * 64];  // 80 KB

  const int t5 = threadIdx.x;
  const int w = t5 >> 6;
  const int l = t5 & 63;

  const int bid = blockIdx.x;   // 512 blocks = 64 rb x 8 hb
  const int hb = bid & 7;       // h-panel -> pinned XCD (round-robin dispatch)
  const int rb = bid >> 3;
  const int bm0 = rb * 256;
  const int h0 = hb * 64;

  const bool isA = (w < 4);

  // staging lane geometry: lane l covers chunk (base + l); r=cidx>>3, c=cidx&7
  const int lrow = l >> 3, lch = l & 7;
  const size_t laneoff = (size_t)lrow * KG + (size_t)((lch ^ lrow) * 8);

  // global base per wave role (A-wave: rows bm0+w*64.. ; B-wave: gate panel)
  const u16* gbase = isA ? (A + (size_t)(bm0 + w * 64) * KG + laneoff)
                         : (Wgt + (size_t)h0 * KG + laneoff);
  // B per-load row offsets (u32, literal-indexed under full unroll)
  u32 boff[10];
  #pragma unroll
  for (int s = 0; s < 10; ++s) {
    int rB = (w - 4) * 80 + s * 8;          // only meaningful for B-waves
    boff[s] = (u32)(((rB >> 6) * Hsz + (rB & 63)) * KG);
  }

#define STAGE(kt) { const u32 _ko = (u32)(kt) * 64; const int _b = (kt) & 1; \
    if (isA) { \
      u16* lb = &LDSA[_b][0] + w * 4096; \
      _Pragma("unroll") \
      for (int s = 0; s < 8; ++s) \
        gload_lds16(gbase + _ko + s * (8 * KG), lb + s * 512); \
    } else { \
      u16* lb = &LDSB[_b][0] + (w - 4) * 5120; \
      _Pragma("unroll") \
      for (int s = 0; s < 10; ++s) \
        gload_lds16(gbase + _ko + boff[s], lb + s * 512); \
    } }

  f32x4 zv = {0.f, 0.f, 0.f, 0.f};
  f32x4 acc[8][5];
  #pragma unroll
  for (int mi = 0; mi < 8; ++mi)
    #pragma unroll
    for (int g = 0; g < 5; ++g) acc[mi][g] = zv;

  // compute-side fragment addresses (u16 indices)
  const int wm = w >> 2;          // M half (128 rows)
  const int wn = w & 3;           // N group (16 cols within each gate's 64)
  const int frow = l & 15;
  const int kq = l >> 4;
  const int f7 = frow & 7;
  const u32 abase  = (u32)((wm * 128 + frow) * 64 + ((kq ^ f7) * 8));
  const u32 bbase  = (u32)((wn * 16 + frow) * 64 + ((kq ^ f7) * 8));
  const u32 abase2 = abase ^ 32;  // kh=1 (chunk XOR 4)
  const u32 bbase2 = bbase ^ 32;

#define LDA4(Asrc, off) { af[0] = *(const bf16x8*)&Asrc[(off)]; \
    af[1] = *(const bf16x8*)&Asrc[(off) + 1024]; \
    af[2] = *(const bf16x8*)&Asrc[(off) + 2048]; \
    af[3] = *(const bf16x8*)&Asrc[(off) + 3072]; }
#define LDB5(Bsrc, off) { bfv[0] = *(const bf16x8*)&Bsrc[(off)]; \
    bfv[1] = *(const bf16x8*)&Bsrc[(off) + 4096]; \
    bfv[2] = *(const bf16x8*)&Bsrc[(off) + 8192]; \
    bfv[3] = *(const bf16x8*)&Bsrc[(off) + 12288]; \
    bfv[4] = *(const bf16x8*)&Bsrc[(off) + 16384]; }
#define MFMA20(base) { __builtin_amdgcn_s_setprio(1); \
    _Pragma("unroll") \
    for (int g = 0; g < 5; ++g) { \
      _Pragma("unroll") \
      for (int mi = 0; mi < 4; ++mi) \
        acc[(base) + mi][g] = __builtin_amdgcn_mfma_f32_16x16x32_bf16( \
            af[mi], bfv[g], acc[(base) + mi][g], 0, 0, 0); \
    } \
    __builtin_amdgcn_s_setprio(0); }

  // prologue: tiles 0,1 in flight
  STAGE(0) STAGE(1)

  for (int t = 0; t < NT2; ++t) {
    const int rem = NT2 - 1 - t;
    if (rem >= 1) { VMCNT(8); } else { VMCNT(0); }
    BAR();
    const u16* As = &LDSA[t & 1][0];
    const u16* Bs = &LDSB[t & 1][0];
    bf16x8 af[4], bfv[5];
    // phase 0: kh0, M-half 0
    LDA4(As, abase) LDB5(Bs, bbase)
    MFMA20(0)
    BAR();
    // phase 1: kh0, M-half 1 (reuse bfv)
    LDA4(As, abase + 4096)
    MFMA20(4)
    BAR();
    // phase 2: kh1, M-half 0
    LDA4(As, abase2) LDB5(Bs, bbase2)
    MFMA20(0)
    BAR();
    // phase 3: kh1, M-half 1
    LDA4(As, abase2 + 4096)
    MFMA20(4)
    BAR();
    if (rem >= 2) STAGE(t + 2)
  }
#undef STAGE

  const int hc = h0 + wn * 16 + frow;
  const float b_f = bg[hc];
  const float b_i = bg[Hsz + hc];
  const float b_T = bg[2 * Hsz + hc];
  const float b_z = bg[3 * Hsz + hc];
  const float b_o = bg[4 * Hsz + hc];
  #pragma unroll
  for (int mi = 0; mi < 8; ++mi) {
    #pragma unroll
    for (int rr = 0; rr < 4; ++rr) {
      const int row = bm0 + wm * 128 + mi * 16 + kq * 4 + rr;
      const float fg = sigm(acc[mi][0][rr] + b_f);
      const float ig = sigm(acc[mi][1][rr] + b_i);
      const float Tg = sigm(acc[mi][2][rr] + b_T);
      const float zg = tanh_(acc[mi][3][rr] + b_z);
      const float og = sigm(acc[mi][4][rr] + b_o);
      const float cp = c_prev[(size_t)row * Hsz + hc];
      const float st = bf2f(A[(size_t)row * KG + 1024 + hc]);
      const float c = fg * cp + ig * zg + Tg * st;
      const float h = og * tanh_(c);
      out[(size_t)row * Hsz + hc] = h;
      out[(size_t)Bsz * Hsz + (size_t)row * Hsz + hc] = c;
    }
  }
}

extern "C" void kernel_launch(void* const* d_in, const int* in_sizes, int n_in,
                              void* d_out, int out_size, void* d_ws, size_t ws_size,
                              hipStream_t stream) {
  const float* x_t    = (const float*)d_in[0];
  const float* delta  = (const float*)d_in[1];
  const float* h_prev = (const float*)d_in[2];
  const float* c_prev = (const float*)d_in[3];
  const float* Ws     = (const float*)d_in[4];
  const float* bs     = (const float*)d_in[5];
  const float* Wg     = (const float*)d_in[6];
  const float* bg     = (const float*)d_in[7];
  float* out = (float*)d_out;

  char* wsb = (char*)d_ws;
  u16* A   = (u16*)(wsb);                          // [16384][1536] bf16
  u16* Wst = (u16*)(wsb + (size_t)50331648);       // [512][1024]  bf16
  u16* Wgt = (u16*)(wsb + (size_t)51380224);       // [2560][1536] bf16

  prep_A_kernel<<<dim3(16384), dim3(256), 0, stream>>>(h_prev, x_t, A);
  transpose_cast_kernel<<<dim3(16, 32), dim3(32, 8), 0, stream>>>(Ws, Wst, 1024, 512);
  transpose_cast_kernel<<<dim3(80, 48), dim3(32, 8), 0, stream>>>(Wg, Wgt, 1536, 2560);
  gemm1_kernel<<<dim3(4, 128), dim3(256), 0, stream>>>(A, Wst, Ws, bs, delta, A);
  gemm2_8ph<<<dim3(512), dim3(512), 0, stream>>>(A, Wgt, bg, c_prev, out);
}

// Round 5
// 200.796 us; speedup vs baseline: 7.4517x; 1.0529x over previous
//
#include <hip/hip_runtime.h>
#include <stdint.h>
#include <stddef.h>

#define Bsz 16384
#define Hsz 512
#define KG 1536   // K of gemm2 == row stride of A
#define KA 1024   // K of gemm1
#define NT3 48    // gemm2 K tiles of 32

typedef float f32x4 __attribute__((ext_vector_type(4)));
typedef short bf16x8 __attribute__((ext_vector_type(8)));
typedef unsigned short u16;
typedef unsigned int u32;

__device__ __forceinline__ u16 f2bf(float f) {
  union { float f; unsigned u; } v; v.f = f;
  return (u16)((v.u + 0x7fffu + ((v.u >> 16) & 1u)) >> 16);
}
__device__ __forceinline__ float bf2f(u16 h) {
  union { unsigned u; float f; } v; v.u = ((unsigned)h) << 16;
  return v.f;
}
__device__ __forceinline__ float sigm(float x) {
  return 1.0f / (1.0f + __expf(-x));
}
__device__ __forceinline__ float tanh_(float x) {
  x = fminf(fmaxf(x, -15.0f), 15.0f);
  float e = __expf(2.0f * x);
  return (e - 1.0f) / (e + 1.0f);
}

__device__ __forceinline__ void gload_lds16(const u16* g, u16* l) {
  __builtin_amdgcn_global_load_lds(
      (__attribute__((address_space(1))) void*)(g),
      (__attribute__((address_space(3))) void*)(l), 16, 0, 0);
}

#define VMCNT(n) asm volatile("s_waitcnt vmcnt(" #n ")" ::: "memory")
#define BAR() { asm volatile("" ::: "memory"); __builtin_amdgcn_s_barrier(); \
                asm volatile("" ::: "memory"); }

// ---- cast h_prev | x_t into bf16 A[B][1536] (cols 0..1023) ----
__global__ __launch_bounds__(256) void prep_A_kernel(
    const float* __restrict__ h_prev, const float* __restrict__ x_t,
    u16* __restrict__ A) {
  const int b = blockIdx.x;
  const int q = threadIdx.x;
  const int qq = q & 127;
  const float4* src = (q < 128) ? (const float4*)h_prev : (const float4*)x_t;
  float4 v = src[(size_t)b * 128 + qq];
  ushort4 o;
  o.x = f2bf(v.x); o.y = f2bf(v.y); o.z = f2bf(v.z); o.w = f2bf(v.w);
  *(ushort4*)(A + (size_t)b * KG + (size_t)q * 4) = o;
}

// ---- transpose-cast: in[R][C] fp32 -> out[C][R] bf16 ----
__global__ __launch_bounds__(256) void transpose_cast_kernel(
    const float* __restrict__ in, u16* __restrict__ out, int R, int C) {
  __shared__ float tile[32][33];
  const int c0 = blockIdx.x * 32;
  const int r0 = blockIdx.y * 32;
  const int tx = threadIdx.x;
  const int ty = threadIdx.y;
  #pragma unroll
  for (int i = ty; i < 32; i += 8)
    tile[i][tx] = in[(size_t)(r0 + i) * C + (c0 + tx)];
  __syncthreads();
  #pragma unroll
  for (int i = ty; i < 32; i += 8)
    out[(size_t)(c0 + i) * R + (r0 + tx)] = f2bf(tile[tx][i]);
}

// ---- GEMM1: s = tanh(A[:,0:1024] @ Wst^T + delta*ws_last + bs) -> A[:,1024:1536]
__global__ __launch_bounds__(256, 2) void gemm1_kernel(
    const u16* __restrict__ A, const u16* __restrict__ Wst,
    const float* __restrict__ Ws, const float* __restrict__ bs,
    const float* __restrict__ delta, u16* __restrict__ Aout) {
  __shared__ __attribute__((aligned(16))) u16 Als[128][32];
  __shared__ __attribute__((aligned(16))) u16 Bls[128][32];
  const int t = threadIdx.x;
  const int w = t >> 6, l = t & 63;
  const int bm0 = blockIdx.y * 128;
  const int bn0 = blockIdx.x * 128;
  const int wm = w >> 1, wn = w & 1;

  f32x4 zv = {0.f, 0.f, 0.f, 0.f};
  f32x4 acc[4][4];
  #pragma unroll
  for (int i = 0; i < 4; ++i)
    #pragma unroll
    for (int j = 0; j < 4; ++j) acc[i][j] = zv;

  const int r = t >> 2, q = t & 3;
  const u16* gA0 = A + (size_t)(bm0 + r) * KG + q * 8;
  const u16* gA1 = A + (size_t)(bm0 + 64 + r) * KG + q * 8;
  const u16* gB0 = Wst + (size_t)(bn0 + r) * KA + q * 8;
  const u16* gB1 = Wst + (size_t)(bn0 + 64 + r) * KA + q * 8;
  u16* lA0 = &Als[0][0] + w * 512;
  u16* lA1 = &Als[0][0] + 2048 + w * 512;
  u16* lB0 = &Bls[0][0] + w * 512;
  u16* lB1 = &Bls[0][0] + 2048 + w * 512;

  const int frow = l & 15;
  const int kofs = (l >> 4) * 8;

  for (int kt = 0; kt < KA / 32; ++kt) {
    const int ko = kt * 32;
    gload_lds16(gA0 + ko, lA0);
    gload_lds16(gA1 + ko, lA1);
    gload_lds16(gB0 + ko, lB0);
    gload_lds16(gB1 + ko, lB1);
    __syncthreads();
    bf16x8 af[4], bfv[4];
    #pragma unroll
    for (int mi = 0; mi < 4; ++mi)
      af[mi] = *(const bf16x8*)&Als[wm * 64 + mi * 16 + frow][kofs];
    #pragma unroll
    for (int ni = 0; ni < 4; ++ni)
      bfv[ni] = *(const bf16x8*)&Bls[wn * 64 + ni * 16 + frow][kofs];
    #pragma unroll
    for (int mi = 0; mi < 4; ++mi)
      #pragma unroll
      for (int ni = 0; ni < 4; ++ni)
        acc[mi][ni] = __builtin_amdgcn_mfma_f32_16x16x32_bf16(
            af[mi], bfv[ni], acc[mi][ni], 0, 0, 0);
    __syncthreads();
  }

  #pragma unroll
  for (int ni = 0; ni < 4; ++ni) {
    const int col = bn0 + wn * 64 + ni * 16 + (l & 15);
    const float wsl = Ws[(size_t)1024 * 512 + col];
    const float bsv = bs[col];
    #pragma unroll
    for (int mi = 0; mi < 4; ++mi) {
      #pragma unroll
      for (int rr = 0; rr < 4; ++rr) {
        const int row = bm0 + wm * 64 + mi * 16 + (l >> 4) * 4 + rr;
        const float z = acc[mi][ni][rr] + delta[row] * wsl + bsv;
        Aout[(size_t)row * KG + 1024 + col] = f2bf(tanh_(z));
      }
    }
  }
}

// ---- GEMM2, m201-faithful 2-phase/tile pipeline ----
// BM=256, N=320 (5 gates x 64 h), BK=32, NT3=48, THREE LDS buffers (108KB),
// 8 waves (2M x 4N), per-wave C = 128x80, acc[8][5] f32x4.
// Stage discipline: during tile t, stage tile t+2 into buffer (t+2)%3,
// spread 2-3 loads per phase, issued AFTER the tile-top barrier.
// Counted vmcnt at tile top only: A-waves vmcnt(4), B-waves vmcnt(5)
// (tile t's loads have 2 full tile-times of slack; never 0 until last tile).
// Phase = {ds_read frags; stage chunk; barrier; setprio+MFMA20; barrier}.
// Chunk swizzle (verified 0-conflict in r2): LDS[r][c]=G[r][c^((r>>1)&3)],
// store via pre-swizzled global src (linear LDS dest), read kq^((frow>>1)&3).
__global__ __launch_bounds__(512, 2) void gemm2_p(
    const u16* __restrict__ A, const u16* __restrict__ Wgt,
    const float* __restrict__ bg, const float* __restrict__ c_prev,
    float* __restrict__ out) {
  __shared__ __attribute__((aligned(16))) u16 LDSA[3][256 * 32];  // 48 KB
  __shared__ __attribute__((aligned(16))) u16 LDSB[3][320 * 32];  // 60 KB

  const int t5 = threadIdx.x;
  const int w = t5 >> 6;
  const int l = t5 & 63;

  const int bid = blockIdx.x;   // 512 blocks = 64 rb x 8 hb
  const int hb = bid & 7;       // h-panel -> pinned XCD (round-robin dispatch)
  const int rb = bid >> 3;
  const int bm0 = rb * 256;
  const int h0 = hb * 64;

  const bool isA = (w < 4);

  const u16* gs0 = nullptr; const u16* gs1 = nullptr; const u16* gs2 = nullptr;
  const u16* gs3 = nullptr; const u16* gs4 = nullptr;
  u32 lo0 = 0, lo1 = 0, lo2 = 0, lo3 = 0, lo4 = 0;

  if (isA) {
#define MKA(s, gp, lo) { int idx = w * 256 + (s) * 64 + l; int row = idx >> 2; \
    int ch = (idx & 3) ^ ((idx >> 3) & 3); \
    gp = A + (size_t)(bm0 + row) * KG + ch * 8; lo = (u32)(w * 256 + (s) * 64) * 8; }
    MKA(0, gs0, lo0) MKA(1, gs1, lo1) MKA(2, gs2, lo2) MKA(3, gs3, lo3)
#undef MKA
  } else {
#define MKB(s, gp, lo) { int idx = (w - 4) * 320 + (s) * 64 + l; int rbw = idx >> 2; \
    int ch = (idx & 3) ^ ((idx >> 3) & 3); \
    int g = rbw >> 6; int hl = rbw & 63; \
    gp = Wgt + (size_t)(g * Hsz + h0 + hl) * KG + ch * 8; \
    lo = (u32)((w - 4) * 320 + (s) * 64) * 8; }
    MKB(0, gs0, lo0) MKB(1, gs1, lo1) MKB(2, gs2, lo2) MKB(3, gs3, lo3) MKB(4, gs4, lo4)
#undef MKB
  }

  // chunk 0: A-waves 2 loads, B-waves 3.  chunk 1: A 2, B 2.
#define STAGE_CH0(kt, bb) { \
    if (isA) { \
      gload_lds16(gs0 + (size_t)(kt) * 32, &LDSA[bb][lo0]); \
      gload_lds16(gs1 + (size_t)(kt) * 32, &LDSA[bb][lo1]); \
    } else { \
      gload_lds16(gs0 + (size_t)(kt) * 32, &LDSB[bb][lo0]); \
      gload_lds16(gs1 + (size_t)(kt) * 32, &LDSB[bb][lo1]); \
      gload_lds16(gs2 + (size_t)(kt) * 32, &LDSB[bb][lo2]); \
    } }
#define STAGE_CH1(kt, bb) { \
    if (isA) { \
      gload_lds16(gs2 + (size_t)(kt) * 32, &LDSA[bb][lo2]); \
      gload_lds16(gs3 + (size_t)(kt) * 32, &LDSA[bb][lo3]); \
    } else { \
      gload_lds16(gs3 + (size_t)(kt) * 32, &LDSB[bb][lo3]); \
      gload_lds16(gs4 + (size_t)(kt) * 32, &LDSB[bb][lo4]); \
    } }

  f32x4 zv = {0.f, 0.f, 0.f, 0.f};
  f32x4 acc[8][5];
  #pragma unroll
  for (int mi = 0; mi < 8; ++mi)
    #pragma unroll
    for (int g = 0; g < 5; ++g) acc[mi][g] = zv;

  const int wm = w >> 2;          // M half (128 rows)
  const int wn = w & 3;           // N group (16 cols within each gate's 64)
  const int frow = l & 15;
  const int kq = l >> 4;
  const u32 axor = (u32)((kq ^ ((frow >> 1) & 3)) << 3);
  const u32 abase = (u32)(wm * 128 + frow) * 32 + axor;
  const u32 bbase = (u32)(wn * 16 + frow) * 32 + axor;

#define LDA4(Asrc, off) { af[0] = *(const bf16x8*)&Asrc[(off)]; \
    af[1] = *(const bf16x8*)&Asrc[(off) + 512]; \
    af[2] = *(const bf16x8*)&Asrc[(off) + 1024]; \
    af[3] = *(const bf16x8*)&Asrc[(off) + 1536]; }
#define LDB5(Bsrc, off) { bfv[0] = *(const bf16x8*)&Bsrc[(off)]; \
    bfv[1] = *(const bf16x8*)&Bsrc[(off) + 2048]; \
    bfv[2] = *(const bf16x8*)&Bsrc[(off) + 4096]; \
    bfv[3] = *(const bf16x8*)&Bsrc[(off) + 6144]; \
    bfv[4] = *(const bf16x8*)&Bsrc[(off) + 8192]; }
#define MFMA20(base) { __builtin_amdgcn_s_setprio(1); \
    _Pragma("unroll") \
    for (int g = 0; g < 5; ++g) { \
      _Pragma("unroll") \
      for (int mi = 0; mi < 4; ++mi) \
        acc[(base) + mi][g] = __builtin_amdgcn_mfma_f32_16x16x32_bf16( \
            af[mi], bfv[g], acc[(base) + mi][g], 0, 0, 0); \
    } \
    __builtin_amdgcn_s_setprio(0); }

  // prologue: tiles 0,1 fully staged (buffers 0,1)
  STAGE_CH0(0, 0) STAGE_CH1(0, 0)
  STAGE_CH0(1, 1) STAGE_CH1(1, 1)

  int bt = 0;                    // t % 3
  int bt2 = 2;                   // (t+2) % 3
  for (int t = 0; t < NT3; ++t) {
    const int rem = NT3 - 1 - t;
    if (rem >= 1) { if (isA) { VMCNT(4); } else { VMCNT(5); } }
    else { VMCNT(0); }
    BAR();
    const u16* As = &LDSA[bt][0];
    const u16* Bs = &LDSB[bt][0];
    bf16x8 af[4], bfv[5];
    // ---- phase 0: M-half 0 ----
    LDA4(As, abase)
    LDB5(Bs, bbase)
    if (rem >= 2) STAGE_CH0(t + 2, bt2)
    BAR();
    MFMA20(0)
    BAR();
    // ---- phase 1: M-half 1 (reuse bfv) ----
    LDA4(As, abase + 2048)
    if (rem >= 2) STAGE_CH1(t + 2, bt2)
    BAR();
    MFMA20(4)
    // no trailing barrier: next tile's top barrier covers the hazard
    bt = (bt == 2) ? 0 : bt + 1;
    bt2 = (bt2 == 2) ? 0 : bt2 + 1;
  }
#undef STAGE_CH0
#undef STAGE_CH1

  const int hc = h0 + wn * 16 + frow;
  const float b_f = bg[hc];
  const float b_i = bg[Hsz + hc];
  const float b_T = bg[2 * Hsz + hc];
  const float b_z = bg[3 * Hsz + hc];
  const float b_o = bg[4 * Hsz + hc];
  #pragma unroll
  for (int mi = 0; mi < 8; ++mi) {
    #pragma unroll
    for (int rr = 0; rr < 4; ++rr) {
      const int row = bm0 + wm * 128 + mi * 16 + kq * 4 + rr;
      const float fg = sigm(acc[mi][0][rr] + b_f);
      const float ig = sigm(acc[mi][1][rr] + b_i);
      const float Tg = sigm(acc[mi][2][rr] + b_T);
      const float zg = tanh_(acc[mi][3][rr] + b_z);
      const float og = sigm(acc[mi][4][rr] + b_o);
      const float cp = c_prev[(size_t)row * Hsz + hc];
      const float st = bf2f(A[(size_t)row * KG + 1024 + hc]);
      const float c = fg * cp + ig * zg + Tg * st;
      const float h = og * tanh_(c);
      out[(size_t)row * Hsz + hc] = h;
      out[(size_t)Bsz * Hsz + (size_t)row * Hsz + hc] = c;
    }
  }
}

extern "C" void kernel_launch(void* const* d_in, const int* in_sizes, int n_in,
                              void* d_out, int out_size, void* d_ws, size_t ws_size,
                              hipStream_t stream) {
  const float* x_t    = (const float*)d_in[0];
  const float* delta  = (const float*)d_in[1];
  const float* h_prev = (const float*)d_in[2];
  const float* c_prev = (const float*)d_in[3];
  const float* Ws     = (const float*)d_in[4];
  const float* bs     = (const float*)d_in[5];
  const float* Wg     = (const float*)d_in[6];
  const float* bg     = (const float*)d_in[7];
  float* out = (float*)d_out;

  char* wsb = (char*)d_ws;
  u16* A   = (u16*)(wsb);                          // [16384][1536] bf16
  u16* Wst = (u16*)(wsb + (size_t)50331648);       // [512][1024]  bf16
  u16* Wgt = (u16*)(wsb + (size_t)51380224);       // [2560][1536] bf16

  prep_A_kernel<<<dim3(16384), dim3(256), 0, stream>>>(h_prev, x_t, A);
  transpose_cast_kernel<<<dim3(16, 32), dim3(32, 8), 0, stream>>>(Ws, Wst, 1024, 512);
  transpose_cast_kernel<<<dim3(80, 48), dim3(32, 8), 0, stream>>>(Wg, Wgt, 1536, 2560);
  gemm1_kernel<<<dim3(4, 128), dim3(256), 0, stream>>>(A, Wst, Ws, bs, delta, A);
  gemm2_p<<<dim3(512), dim3(512), 0, stream>>>(A, Wgt, bg, c_prev, out);
}